// Round 10
// baseline (359.834 us; speedup 1.0000x reference)
//
#include <hip/hip_runtime.h>
#include <math.h>

#define NN 16000
#define NE 256000

// ---------- helpers ----------

// dot of h[16] (registers) with 16 contiguous weight coefficients in LDS
// (wave-uniform address -> broadcast ds_read, conflict-free)
__device__ __forceinline__ float wdot(const float* wt, const float* h) {
    float w = 0.f;
#pragma unroll
    for (int c = 0; c < 16; ++c) w = fmaf(h[c], wt[c], w);
    return w;
}

// segmented run-sum within a wave (edges sorted by src; runs contiguous)
__device__ __forceinline__ float segsum(float v, unsigned addmask) {
#pragma unroll
    for (int k = 0, off = 1; off < 64; ++k, off <<= 1) {
        float ov = __shfl_down(v, off);
        if (addmask & (1u << k)) v += ov;
    }
    return v;
}

// TP scale constants (fp32, match reference formulas)
#define C_000 0.17677669529663687f   // 1/(sqrt(16)*sqrt(2))
#define C_110 0.14433756729740643f   // 1/sqrt(48)
#define C_011 0.14433756729740643f   // 1/sqrt(48)
#define C_101 0.20412414523193148f   // 1/sqrt(24)
#define RS10  0.31622776601683794f   // 1/sqrt(10)
#define RS12  0.28867513459481287f   // 1/sqrt(12)

// ---------- prep: transpose W2 matrices (and fold the /sqrt(16)=0.25) ----------
__global__ void prep_kernel(const float* __restrict__ Wk2, const float* __restrict__ Wv2,
                            float* __restrict__ Wk2t, float* __restrict__ Wv2t) {
    int tid = blockIdx.x * blockDim.x + threadIdx.x;
    if (tid < 320 * 16) {
        int j = tid >> 4, c = tid & 15;
        Wk2t[tid] = 0.25f * Wk2[c * 320 + j];
    }
    int t2 = tid - 320 * 16;
    if (t2 >= 0 && t2 < 640 * 16) {
        int j = t2 >> 4, c = t2 & 15;
        Wv2t[t2] = 0.25f * Wv2[c * 640 + j];
    }
}

// ---------- q = linear_equiv(feature) ----------
__global__ void q_kernel(const float* __restrict__ feature,
                         const float* __restrict__ Wq0, const float* __restrict__ Wq1,
                         float* __restrict__ qbuf) {
    int n = blockIdx.x * blockDim.x + threadIdx.x;
    if (n >= NN) return;
    const float4* f4 = (const float4*)(feature + n * 40);
    float xr[40];
#pragma unroll
    for (int i = 0; i < 10; ++i) {
        float4 t = f4[i];
        xr[i * 4 + 0] = t.x; xr[i * 4 + 1] = t.y; xr[i * 4 + 2] = t.z; xr[i * 4 + 3] = t.w;
    }
    float* qr = qbuf + n * 20;
#pragma unroll 1
    for (int o = 0; o < 8; ++o) {
        float a = 0.f;
#pragma unroll
        for (int i = 0; i < 16; ++i) a = fmaf(xr[i], Wq0[i * 8 + o], a);
        qr[o] = 0.25f * a;
    }
#pragma unroll 1
    for (int o = 0; o < 4; ++o) {
        float a0 = 0.f, a1 = 0.f, a2 = 0.f;
#pragma unroll
        for (int i = 0; i < 8; ++i) {
            float w = Wq1[i * 4 + o];
            a0 = fmaf(xr[16 + i * 3 + 0], w, a0);
            a1 = fmaf(xr[16 + i * 3 + 1], w, a1);
            a2 = fmaf(xr[16 + i * 3 + 2], w, a2);
        }
        qr[8 + o * 3 + 0] = 0.35355339059327373f * a0;
        qr[8 + o * 3 + 1] = 0.35355339059327373f * a1;
        qr[8 + o * 3 + 2] = 0.35355339059327373f * a2;
    }
}

// ---------- counting sort of edges by src ----------
__global__ void hist_kernel(const int* __restrict__ esrc, int* __restrict__ cnt) {
    int e = blockIdx.x * blockDim.x + threadIdx.x;
    if (e < NE) atomicAdd(cnt + esrc[e], 1);
}

__global__ void scan_kernel(const int* __restrict__ cnt,
                            int* __restrict__ rowstart, int* __restrict__ cursor) {
    __shared__ int part[1024];
    int t = threadIdx.x;
    int base = t * 16;
    int local[16];
    int s = 0;
#pragma unroll
    for (int j = 0; j < 16; ++j) {
        int idx = base + j;
        int c = (idx < NN) ? cnt[idx] : 0;
        local[j] = s;
        s += c;
    }
    part[t] = s;
    __syncthreads();
    for (int off = 1; off < 1024; off <<= 1) {
        int v = (t >= off) ? part[t - off] : 0;
        __syncthreads();
        part[t] += v;
        __syncthreads();
    }
    int excl = part[t] - s;
#pragma unroll
    for (int j = 0; j < 16; ++j) {
        int idx = base + j;
        if (idx < NN) {
            int val = excl + local[j];
            rowstart[idx] = val;
            cursor[idx] = val;
        } else if (idx == NN) {
            rowstart[NN] = excl + local[j];
        }
    }
}

// scatter: materialize sorted esh/elen so heavy kernels read coalesced
__global__ void scatter_kernel(const int* __restrict__ esrc, const int* __restrict__ edst,
                               const float* __restrict__ esh, const float* __restrict__ elen,
                               int* __restrict__ cursor,
                               int* __restrict__ srcS, int* __restrict__ dstS,
                               float* __restrict__ shS, float* __restrict__ elenS) {
    int e = blockIdx.x * blockDim.x + threadIdx.x;
    if (e >= NE) return;
    int src = esrc[e];
    int pos = atomicAdd(cursor + src, 1);
    srcS[pos] = src;
    dstS[pos] = edst[e];
    *(float4*)(shS + pos * 4) = *(const float4*)(esh + e * 4);
    const float2* ep = (const float2*)(elen + e * 10);
    float2* op = (float2*)(elenS + pos * 10);
#pragma unroll
    for (int j = 0; j < 5; ++j) op[j] = ep[j];
}

// ---------- per-edge k path (sorted): logit, weights staged in LDS ----------
// 512-thread blocks: 20KB LDS -> LDS never caps; occupancy limited by VGPR/HW (32 waves/CU)
__global__ __launch_bounds__(512)
void k_kernel(const int* __restrict__ srcS, const int* __restrict__ dstS,
              const float* __restrict__ shS, const float* __restrict__ elenS,
              const float* __restrict__ feature, const float* __restrict__ qbuf,
              const float* __restrict__ Wk1, const float* __restrict__ Wk2t,
              float* __restrict__ logitbuf) {
    __shared__ float W[5120];   // 20 KB: full Wk2t
    {
        float4* dst4 = (float4*)W;
        const float4* src4 = (const float4*)Wk2t;
        for (int i = threadIdx.x; i < 1280; i += 512) dst4[i] = src4[i];
    }
    __syncthreads();

    int sidx = blockIdx.x * blockDim.x + threadIdx.x;
    if (sidx >= NE) return;
    int src = srcS[sidx], dst = dstS[sidx];

    float4 shv = *(const float4*)(shS + sidx * 4);
    float sh0 = shv.x, sh1x = shv.y, sh1y = shv.z, sh1z = shv.w;

    float el[10];
    {
        const float2* ep = (const float2*)(elenS + sidx * 10);
#pragma unroll
        for (int j = 0; j < 5; ++j) { float2 t = ep[j]; el[j * 2] = t.x; el[j * 2 + 1] = t.y; }
    }
    float h[16];
    {
        float acc[16];
#pragma unroll
        for (int j = 0; j < 16; ++j) acc[j] = 0.f;
#pragma unroll
        for (int c = 0; c < 10; ++c) {
            float ec = el[c];
#pragma unroll
            for (int j = 0; j < 16; ++j) acc[j] = fmaf(ec, Wk1[c * 16 + j], acc[j]);
        }
#pragma unroll
        for (int j = 0; j < 16; ++j) {
            float s = acc[j] * RS10;
            h[j] = s / (1.f + __expf(-s));
        }
    }

    const float4* f4 = (const float4*)(feature + dst * 40);
    float xr[40];
#pragma unroll
    for (int i = 0; i < 10; ++i) {
        float4 t = f4[i];
        xr[i * 4 + 0] = t.x; xr[i * 4 + 1] = t.y; xr[i * 4 + 2] = t.z; xr[i * 4 + 3] = t.w;
    }
    float x0[16];
#pragma unroll
    for (int i = 0; i < 16; ++i) x0[i] = xr[i];
    float x1[8][3], d1[8], cx[8][3];
#pragma unroll
    for (int i = 0; i < 8; ++i) {
        float a = xr[16 + i * 3 + 0], b = xr[16 + i * 3 + 1], c = xr[16 + i * 3 + 2];
        x1[i][0] = a; x1[i][1] = b; x1[i][2] = c;
        d1[i] = a * sh1x + b * sh1y + c * sh1z;
        cx[i][0] = b * sh1z - c * sh1y;
        cx[i][1] = c * sh1x - a * sh1z;
        cx[i][2] = a * sh1y - b * sh1x;
    }

    const float* qr = qbuf + src * 20;
    float logit = 0.f;

#pragma unroll 1
    for (int o = 0; o < 8; ++o) {
        float e000 = 0.f, e110 = 0.f;
#pragma unroll
        for (int i = 0; i < 16; ++i)
            e000 = fmaf(x0[i], wdot(W + (i * 8 + o) * 16, h), e000);
#pragma unroll
        for (int i = 0; i < 8; ++i)
            e110 = fmaf(d1[i], wdot(W + ((128 + i * 8 + o)) * 16, h), e110);
        float ko = fmaf(C_000 * sh0, e000, C_110 * e110);
        logit = fmaf(qr[o], ko, logit);
    }
#pragma unroll 1
    for (int o = 0; o < 4; ++o) {
        float c0 = 0.f;
#pragma unroll
        for (int i = 0; i < 16; ++i)
            c0 = fmaf(x0[i], wdot(W + ((192 + i * 4 + o)) * 16, h), c0);
        float s1x = 0.f, s1y = 0.f, s1z = 0.f, s2x = 0.f, s2y = 0.f, s2z = 0.f;
#pragma unroll
        for (int i = 0; i < 8; ++i) {
            float wa = wdot(W + ((256 + i * 4 + o)) * 16, h);
            float wb = wdot(W + ((288 + i * 4 + o)) * 16, h);
            s1x = fmaf(x1[i][0], wa, s1x); s1y = fmaf(x1[i][1], wa, s1y); s1z = fmaf(x1[i][2], wa, s1z);
            s2x = fmaf(cx[i][0], wb, s2x); s2y = fmaf(cx[i][1], wb, s2y); s2z = fmaf(cx[i][2], wb, s2z);
        }
        float kx = C_011 * fmaf(c0, sh1x, s2x) + C_101 * sh0 * s1x;
        float ky = C_011 * fmaf(c0, sh1y, s2y) + C_101 * sh0 * s1y;
        float kz = C_011 * fmaf(c0, sh1z, s2z) + C_101 * sh0 * s1z;
        logit = fmaf(qr[8 + o * 3 + 0], kx, logit);
        logit = fmaf(qr[8 + o * 3 + 1], ky, logit);
        logit = fmaf(qr[8 + o * 3 + 2], kz, logit);
    }

    logitbuf[sidx] = logit * RS12;
}

// ---------- per-node logZ from contiguous logit segment ----------
__global__ void mz_kernel(const int* __restrict__ rowstart,
                          const float* __restrict__ logitbuf, float* __restrict__ logZ) {
    int n = blockIdx.x * blockDim.x + threadIdx.x;
    if (n >= NN) return;
    int b = rowstart[n], e2 = rowstart[n + 1];
    if (b >= e2) { logZ[n] = 0.f; return; }
    float m = -INFINITY;
    for (int i = b; i < e2; ++i) m = fmaxf(m, logitbuf[i]);
    float z = 0.f;
    for (int i = b; i < e2; ++i) z += __expf(logitbuf[i] - m);
    logZ[n] = m + __logf(z);
}

// ---------- per-edge v path (sorted): weights in LDS, narrow segsum ----------
// 512-thread blocks: 4 blocks x 40KB = 160KiB exactly -> 32 waves/CU (HW max)
__global__ __launch_bounds__(512)
void v_kernel(const int* __restrict__ srcS, const int* __restrict__ dstS,
              const float* __restrict__ shS, const float* __restrict__ elenS,
              const float* __restrict__ feature,
              const float* __restrict__ logitbuf, const float* __restrict__ logZ,
              const float* __restrict__ Wv1, const float* __restrict__ Wv2t,
              float* __restrict__ out) {
    __shared__ float W[10240];  // 40 KB: full Wv2t
    {
        float4* dst4 = (float4*)W;
        const float4* src4 = (const float4*)Wv2t;
        for (int i = threadIdx.x; i < 2560; i += 512) dst4[i] = src4[i];
    }
    __syncthreads();

    int sidx = blockIdx.x * blockDim.x + threadIdx.x;
    if (sidx >= NE) return;
    int src = srcS[sidx], dst = dstS[sidx];
    int lane = threadIdx.x & 63;

    int srcPrev = __shfl_up(src, 1);
    bool head = (lane == 0) || (srcPrev != src);
    unsigned addmask = 0;
#pragma unroll
    for (int k = 0, off = 1; off < 64; ++k, off <<= 1) {
        int os = __shfl_down(src, off);
        if ((lane + off) < 64 && os == src) addmask |= (1u << k);
    }

    float alpha = __expf(logitbuf[sidx] - logZ[src]);

    float4 shv = *(const float4*)(shS + sidx * 4);
    float sh0 = shv.x, sh1x = shv.y, sh1y = shv.z, sh1z = shv.w;

    float el[10];
    {
        const float2* ep = (const float2*)(elenS + sidx * 10);
#pragma unroll
        for (int j = 0; j < 5; ++j) { float2 t = ep[j]; el[j * 2] = t.x; el[j * 2 + 1] = t.y; }
    }
    float h[16];
    {
        float acc[16];
#pragma unroll
        for (int j = 0; j < 16; ++j) acc[j] = 0.f;
#pragma unroll
        for (int c = 0; c < 10; ++c) {
            float ec = el[c];
#pragma unroll
            for (int j = 0; j < 16; ++j) acc[j] = fmaf(ec, Wv1[c * 16 + j], acc[j]);
        }
#pragma unroll
        for (int j = 0; j < 16; ++j) {
            float s = acc[j] * RS10;
            h[j] = s / (1.f + __expf(-s));
        }
    }

    const float4* f4 = (const float4*)(feature + dst * 40);
    float xr[40];
#pragma unroll
    for (int i = 0; i < 10; ++i) {
        float4 t = f4[i];
        xr[i * 4 + 0] = t.x; xr[i * 4 + 1] = t.y; xr[i * 4 + 2] = t.z; xr[i * 4 + 3] = t.w;
    }
    float x0[16];
#pragma unroll
    for (int i = 0; i < 16; ++i) x0[i] = xr[i];
    float x1[8][3], d1[8], cx[8][3];
#pragma unroll
    for (int i = 0; i < 8; ++i) {
        float a = xr[16 + i * 3 + 0], b = xr[16 + i * 3 + 1], c = xr[16 + i * 3 + 2];
        x1[i][0] = a; x1[i][1] = b; x1[i][2] = c;
        d1[i] = a * sh1x + b * sh1y + c * sh1z;
        cx[i][0] = b * sh1z - c * sh1y;
        cx[i][1] = c * sh1x - a * sh1z;
        cx[i][2] = a * sh1y - b * sh1x;
    }

    float* orow = out + src * 40;

    // scalar (l=0) outputs of v: o in [0,16)
#pragma unroll 1
    for (int o = 0; o < 16; ++o) {
        float e000 = 0.f, e110 = 0.f;
#pragma unroll
        for (int i = 0; i < 16; ++i)
            e000 = fmaf(x0[i], wdot(W + (i * 16 + o) * 16, h), e000);
#pragma unroll
        for (int i = 0; i < 8; ++i)
            e110 = fmaf(d1[i], wdot(W + ((256 + i * 16 + o)) * 16, h), e110);
        float vo = alpha * fmaf(C_000 * sh0, e000, C_110 * e110);
        vo = segsum(vo, addmask);
        if (head) atomicAdd(orow + o, vo);
    }
    // vector (l=1) outputs of v: o in [0,8)
#pragma unroll 1
    for (int o = 0; o < 8; ++o) {
        float c0 = 0.f;
#pragma unroll
        for (int i = 0; i < 16; ++i)
            c0 = fmaf(x0[i], wdot(W + ((384 + i * 8 + o)) * 16, h), c0);
        float s1x = 0.f, s1y = 0.f, s1z = 0.f, s2x = 0.f, s2y = 0.f, s2z = 0.f;
#pragma unroll
        for (int i = 0; i < 8; ++i) {
            float wa = wdot(W + ((512 + i * 8 + o)) * 16, h);
            float wb = wdot(W + ((576 + i * 8 + o)) * 16, h);
            s1x = fmaf(x1[i][0], wa, s1x); s1y = fmaf(x1[i][1], wa, s1y); s1z = fmaf(x1[i][2], wa, s1z);
            s2x = fmaf(cx[i][0], wb, s2x); s2y = fmaf(cx[i][1], wb, s2y); s2z = fmaf(cx[i][2], wb, s2z);
        }
        float vx = alpha * (C_011 * fmaf(c0, sh1x, s2x) + C_101 * sh0 * s1x);
        float vy = alpha * (C_011 * fmaf(c0, sh1y, s2y) + C_101 * sh0 * s1y);
        float vz = alpha * (C_011 * fmaf(c0, sh1z, s2z) + C_101 * sh0 * s1z);
        vx = segsum(vx, addmask);
        vy = segsum(vy, addmask);
        vz = segsum(vz, addmask);
        if (head) {
            atomicAdd(orow + 16 + o * 3 + 0, vx);
            atomicAdd(orow + 16 + o * 3 + 1, vy);
            atomicAdd(orow + 16 + o * 3 + 2, vz);
        }
    }
}

// ---------- host ----------
extern "C" void kernel_launch(void* const* d_in, const int* in_sizes, int n_in,
                              void* d_out, int out_size, void* d_ws, size_t ws_size,
                              hipStream_t stream) {
    const float* feature = (const float*)d_in[0];
    const int*   esrc    = (const int*)d_in[1];
    const int*   edst    = (const int*)d_in[2];
    const float* esh     = (const float*)d_in[3];
    const float* elen    = (const float*)d_in[4];
    const float* Wq0     = (const float*)d_in[5];
    const float* Wq1     = (const float*)d_in[6];
    const float* Wk1     = (const float*)d_in[7];
    const float* Wk2     = (const float*)d_in[8];
    const float* Wv1     = (const float*)d_in[9];
    const float* Wv2     = (const float*)d_in[10];
    float* out = (float*)d_out;

    float* ws = (float*)d_ws;
    float* qbuf     = ws;                         // 320000
    float* logitbuf = ws + 320000;                // 256000
    float* logZ     = ws + 576000;                // 16000
    float* Wk2t     = ws + 592000;                // 5120
    float* Wv2t     = ws + 597120;                // 10240
    int*   cnt      = (int*)(ws + 607360);        // 16000
    int*   rowstart = (int*)(ws + 623360);        // 16001
    int*   cursor   = (int*)(ws + 639361);        // 16000
    int*   srcS     = (int*)(ws + 655361);        // 256000
    int*   dstS     = (int*)(ws + 911361);        // 256000
    float* shS      = ws + 1167364;               // 1024000 (16B aligned)
    float* elenS    = ws + 2191364;               // 2560000 (8B aligned)

    hipMemsetAsync(cnt, 0, NN * sizeof(int), stream);
    hipMemsetAsync(out, 0, (size_t)out_size * sizeof(float), stream);

    prep_kernel<<<60, 256, 0, stream>>>(Wk2, Wv2, Wk2t, Wv2t);
    q_kernel<<<(NN + 255) / 256, 256, 0, stream>>>(feature, Wq0, Wq1, qbuf);
    hist_kernel<<<NE / 256, 256, 0, stream>>>(esrc, cnt);
    scan_kernel<<<1, 1024, 0, stream>>>(cnt, rowstart, cursor);
    scatter_kernel<<<NE / 256, 256, 0, stream>>>(esrc, edst, esh, elen, cursor,
                                                 srcS, dstS, shS, elenS);
    k_kernel<<<NE / 512, 512, 0, stream>>>(srcS, dstS, shS, elenS, feature, qbuf,
                                           Wk1, Wk2t, logitbuf);
    mz_kernel<<<(NN + 255) / 256, 256, 0, stream>>>(rowstart, logitbuf, logZ);
    v_kernel<<<NE / 512, 512, 0, stream>>>(srcS, dstS, shS, elenS, feature,
                                           logitbuf, logZ, Wv1, Wv2t, out);
}

// Round 14
// 332.792 us; speedup vs baseline: 1.0813x; 1.0813x over previous
//
#include <hip/hip_runtime.h>
#include <math.h>

#define NN 16000
#define NE 256000

// ---------- helpers ----------

// dot of h[16] with 16 contiguous weight coefficients (LDS broadcast or
// wave-uniform global). Two accumulator chains for 2x ILP.
__device__ __forceinline__ float wdot(const float* wt, const float* h) {
    float a = 0.f, b = 0.f;
#pragma unroll
    for (int c = 0; c < 16; c += 2) {
        a = fmaf(h[c], wt[c], a);
        b = fmaf(h[c + 1], wt[c + 1], b);
    }
    return a + b;
}

// segmented run-sum within a wave (edges sorted by src; runs contiguous)
__device__ __forceinline__ float segsum(float v, unsigned addmask) {
#pragma unroll
    for (int k = 0, off = 1; off < 64; ++k, off <<= 1) {
        float ov = __shfl_down(v, off);
        if (addmask & (1u << k)) v += ov;
    }
    return v;
}

// TP scale constants (folded into weights at prep; kept for reference)
#define C_000 0.17677669529663687f   // 1/(sqrt(16)*sqrt(2))
#define C_110 0.14433756729740643f   // 1/sqrt(48)
#define C_011 0.14433756729740643f   // 1/sqrt(48)  (also = C_111)
#define C_101 0.20412414523193148f   // 1/sqrt(24)
#define RS10  0.31622776601683794f   // 1/sqrt(10)
#define RS12  0.28867513459481287f   // 1/sqrt(12)  (folded into q)

// ---------- prep: transpose W2, fold 0.25 (=1/sqrt(16)) and TP constants ----------
__global__ void prep_kernel(const float* __restrict__ Wk2, const float* __restrict__ Wv2,
                            float* __restrict__ Wk2t, float* __restrict__ Wv2t) {
    int tid = blockIdx.x * blockDim.x + threadIdx.x;
    if (tid < 320 * 16) {
        int j = tid >> 4, c = tid & 15;
        float s = (j < 128) ? C_000 : (j < 192) ? C_110 : (j < 256) ? C_011
                : (j < 288) ? C_101 : C_011;  // 111 shares 1/sqrt(48)
        Wk2t[tid] = 0.25f * s * Wk2[c * 320 + j];
    }
    int t2 = tid - 320 * 16;
    if (t2 >= 0 && t2 < 640 * 16) {
        int j = t2 >> 4, c = t2 & 15;
        float s = (j < 256) ? C_000 : (j < 384) ? C_110 : (j < 512) ? C_011
                : (j < 576) ? C_101 : C_011;
        Wv2t[t2] = 0.25f * s * Wv2[c * 640 + j];
    }
}

// ---------- q = linear_equiv(feature), with 1/sqrt(12) logit scale folded in ----------
__global__ void q_kernel(const float* __restrict__ feature,
                         const float* __restrict__ Wq0, const float* __restrict__ Wq1,
                         float* __restrict__ qbuf) {
    int n = blockIdx.x * blockDim.x + threadIdx.x;
    if (n >= NN) return;
    const float4* f4 = (const float4*)(feature + n * 40);
    float xr[40];
#pragma unroll
    for (int i = 0; i < 10; ++i) {
        float4 t = f4[i];
        xr[i * 4 + 0] = t.x; xr[i * 4 + 1] = t.y; xr[i * 4 + 2] = t.z; xr[i * 4 + 3] = t.w;
    }
    float* qr = qbuf + n * 20;
#pragma unroll 1
    for (int o = 0; o < 8; ++o) {
        float a = 0.f;
#pragma unroll
        for (int i = 0; i < 16; ++i) a = fmaf(xr[i], Wq0[i * 8 + o], a);
        qr[o] = (0.25f * RS12) * a;
    }
#pragma unroll 1
    for (int o = 0; o < 4; ++o) {
        float a0 = 0.f, a1 = 0.f, a2 = 0.f;
#pragma unroll
        for (int i = 0; i < 8; ++i) {
            float w = Wq1[i * 4 + o];
            a0 = fmaf(xr[16 + i * 3 + 0], w, a0);
            a1 = fmaf(xr[16 + i * 3 + 1], w, a1);
            a2 = fmaf(xr[16 + i * 3 + 2], w, a2);
        }
        qr[8 + o * 3 + 0] = (0.35355339059327373f * RS12) * a0;
        qr[8 + o * 3 + 1] = (0.35355339059327373f * RS12) * a1;
        qr[8 + o * 3 + 2] = (0.35355339059327373f * RS12) * a2;
    }
}

// ---------- counting sort of edges by src ----------
__global__ void hist_kernel(const int* __restrict__ esrc, int* __restrict__ cnt) {
    int e = blockIdx.x * blockDim.x + threadIdx.x;
    if (e < NE) atomicAdd(cnt + esrc[e], 1);
}

__global__ void scan_kernel(const int* __restrict__ cnt,
                            int* __restrict__ rowstart, int* __restrict__ cursor) {
    __shared__ int part[1024];
    int t = threadIdx.x;
    int base = t * 16;
    int local[16];
    int s = 0;
#pragma unroll
    for (int j = 0; j < 16; ++j) {
        int idx = base + j;
        int c = (idx < NN) ? cnt[idx] : 0;
        local[j] = s;
        s += c;
    }
    part[t] = s;
    __syncthreads();
    for (int off = 1; off < 1024; off <<= 1) {
        int v = (t >= off) ? part[t - off] : 0;
        __syncthreads();
        part[t] += v;
        __syncthreads();
    }
    int excl = part[t] - s;
#pragma unroll
    for (int j = 0; j < 16; ++j) {
        int idx = base + j;
        if (idx < NN) {
            int val = excl + local[j];
            rowstart[idx] = val;
            cursor[idx] = val;
        } else if (idx == NN) {
            rowstart[NN] = excl + local[j];
        }
    }
}

// scatter: materialize sorted esh/elen so heavy kernels read coalesced
__global__ void scatter_kernel(const int* __restrict__ esrc, const int* __restrict__ edst,
                               const float* __restrict__ esh, const float* __restrict__ elen,
                               int* __restrict__ cursor,
                               int* __restrict__ srcS, int* __restrict__ dstS,
                               float* __restrict__ shS, float* __restrict__ elenS) {
    int e = blockIdx.x * blockDim.x + threadIdx.x;
    if (e >= NE) return;
    int src = esrc[e];
    int pos = atomicAdd(cursor + src, 1);
    srcS[pos] = src;
    dstS[pos] = edst[e];
    *(float4*)(shS + pos * 4) = *(const float4*)(esh + e * 4);
    const float2* ep = (const float2*)(elen + e * 10);
    float2* op = (float2*)(elenS + pos * 10);
#pragma unroll
    for (int j = 0; j < 5; ++j) op[j] = ep[j];
}

// ---------- per-edge k path (sorted): logit; weights (consts folded) in LDS ----------
// 20KB LDS, 512 threads -> wave-capped 4 blocks/CU = 32 waves (HW max)
__global__ __launch_bounds__(512)
void k_kernel(const int* __restrict__ srcS, const int* __restrict__ dstS,
              const float* __restrict__ shS, const float* __restrict__ elenS,
              const float* __restrict__ feature, const float* __restrict__ qbuf,
              const float* __restrict__ Wk1, const float* __restrict__ Wk2t,
              float* __restrict__ logitbuf) {
    __shared__ float W[5120];   // 20 KB: full Wk2t
    {
        float4* dst4 = (float4*)W;
        const float4* src4 = (const float4*)Wk2t;
        for (int i = threadIdx.x; i < 1280; i += 512) dst4[i] = src4[i];
    }
    __syncthreads();

    int sidx = blockIdx.x * blockDim.x + threadIdx.x;
    if (sidx >= NE) return;
    int src = srcS[sidx], dst = dstS[sidx];

    float4 shv = *(const float4*)(shS + sidx * 4);
    float sh1x = shv.y, sh1y = shv.z, sh1z = shv.w;  // sh0 == 1.0 by construction

    float el[10];
    {
        const float2* ep = (const float2*)(elenS + sidx * 10);
#pragma unroll
        for (int j = 0; j < 5; ++j) { float2 t = ep[j]; el[j * 2] = t.x; el[j * 2 + 1] = t.y; }
    }
    float h[16];
    {
        float acc[16];
#pragma unroll
        for (int j = 0; j < 16; ++j) acc[j] = 0.f;
#pragma unroll
        for (int c = 0; c < 10; ++c) {
            float ec = el[c];
#pragma unroll
            for (int j = 0; j < 16; ++j) acc[j] = fmaf(ec, Wk1[c * 16 + j], acc[j]);
        }
#pragma unroll
        for (int j = 0; j < 16; ++j) {
            float s = acc[j] * RS10;
            h[j] = s / (1.f + __expf(-s));
        }
    }

    const float4* f4 = (const float4*)(feature + dst * 40);
    float xr[40];
#pragma unroll
    for (int i = 0; i < 10; ++i) {
        float4 t = f4[i];
        xr[i * 4 + 0] = t.x; xr[i * 4 + 1] = t.y; xr[i * 4 + 2] = t.z; xr[i * 4 + 3] = t.w;
    }
    float x0[16];
#pragma unroll
    for (int i = 0; i < 16; ++i) x0[i] = xr[i];
    float x1[8][3], d1[8], cx[8][3];
#pragma unroll
    for (int i = 0; i < 8; ++i) {
        float a = xr[16 + i * 3 + 0], b = xr[16 + i * 3 + 1], c = xr[16 + i * 3 + 2];
        x1[i][0] = a; x1[i][1] = b; x1[i][2] = c;
        d1[i] = a * sh1x + b * sh1y + c * sh1z;
        cx[i][0] = b * sh1z - c * sh1y;
        cx[i][1] = c * sh1x - a * sh1z;
        cx[i][2] = a * sh1y - b * sh1x;
    }

    const float* qr = qbuf + src * 20;
    float logit = 0.f;

#pragma unroll 1
    for (int o = 0; o < 8; ++o) {
        float e000 = 0.f, e110 = 0.f;
#pragma unroll
        for (int i = 0; i < 16; ++i)
            e000 = fmaf(x0[i], wdot(W + (i * 8 + o) * 16, h), e000);
#pragma unroll
        for (int i = 0; i < 8; ++i)
            e110 = fmaf(d1[i], wdot(W + ((128 + i * 8 + o)) * 16, h), e110);
        logit = fmaf(qr[o], e000 + e110, logit);   // constants folded; sh0==1
    }
#pragma unroll 1
    for (int o = 0; o < 4; ++o) {
        float c0 = 0.f;
#pragma unroll
        for (int i = 0; i < 16; ++i)
            c0 = fmaf(x0[i], wdot(W + ((192 + i * 4 + o)) * 16, h), c0);
        float s1x = 0.f, s1y = 0.f, s1z = 0.f, s2x = 0.f, s2y = 0.f, s2z = 0.f;
#pragma unroll
        for (int i = 0; i < 8; ++i) {
            float wa = wdot(W + ((256 + i * 4 + o)) * 16, h);
            float wb = wdot(W + ((288 + i * 4 + o)) * 16, h);
            s1x = fmaf(x1[i][0], wa, s1x); s1y = fmaf(x1[i][1], wa, s1y); s1z = fmaf(x1[i][2], wa, s1z);
            s2x = fmaf(cx[i][0], wb, s2x); s2y = fmaf(cx[i][1], wb, s2y); s2z = fmaf(cx[i][2], wb, s2z);
        }
        float kx = s1x + fmaf(c0, sh1x, s2x);
        float ky = s1y + fmaf(c0, sh1y, s2y);
        float kz = s1z + fmaf(c0, sh1z, s2z);
        logit = fmaf(qr[8 + o * 3 + 0], kx, logit);
        logit = fmaf(qr[8 + o * 3 + 1], ky, logit);
        logit = fmaf(qr[8 + o * 3 + 2], kz, logit);
    }

    logitbuf[sidx] = logit;   // 1/sqrt(12) folded into q
}

// ---------- per-node logZ from contiguous logit segment ----------
__global__ void mz_kernel(const int* __restrict__ rowstart,
                          const float* __restrict__ logitbuf, float* __restrict__ logZ) {
    int n = blockIdx.x * blockDim.x + threadIdx.x;
    if (n >= NN) return;
    int b = rowstart[n], e2 = rowstart[n + 1];
    if (b >= e2) { logZ[n] = 0.f; return; }
    float m = -INFINITY;
    for (int i = b; i < e2; ++i) m = fmaxf(m, logitbuf[i]);
    float z = 0.f;
    for (int i = b; i < e2; ++i) z += __expf(logitbuf[i] - m);
    logZ[n] = m + __logf(z);
}

// ---------- per-edge v path (sorted): 32KB LDS (W000/110/011), W101/111 from
// global (8KB, L1-resident, wave-uniform); alpha folded into h ----------
// 4 blocks x 32KB = 128KB LDS -> 32 waves/CU at VGPR<=64
__global__ __launch_bounds__(512)
void v_kernel(const int* __restrict__ srcS, const int* __restrict__ dstS,
              const float* __restrict__ shS, const float* __restrict__ elenS,
              const float* __restrict__ feature,
              const float* __restrict__ logitbuf, const float* __restrict__ logZ,
              const float* __restrict__ Wv1, const float* __restrict__ Wv2t,
              float* __restrict__ out) {
    __shared__ float W[8192];  // 32 KB: W000 + W110 + W011 (j < 512)
    {
        float4* dst4 = (float4*)W;
        const float4* src4 = (const float4*)Wv2t;
        for (int i = threadIdx.x; i < 2048; i += 512) dst4[i] = src4[i];
    }
    const float* WG = Wv2t + 8192;   // W101 (64 rows) + W111 (64 rows), global
    __syncthreads();

    int sidx = blockIdx.x * blockDim.x + threadIdx.x;
    if (sidx >= NE) return;
    int src = srcS[sidx], dst = dstS[sidx];
    int lane = threadIdx.x & 63;

    int srcPrev = __shfl_up(src, 1);
    bool head = (lane == 0) || (srcPrev != src);
    unsigned addmask = 0;
#pragma unroll
    for (int k = 0, off = 1; off < 64; ++k, off <<= 1) {
        int os = __shfl_down(src, off);
        if ((lane + off) < 64 && os == src) addmask |= (1u << k);
    }

    float alpha = __expf(logitbuf[sidx] - logZ[src]);

    float4 shv = *(const float4*)(shS + sidx * 4);
    float sh1x = shv.y, sh1y = shv.z, sh1z = shv.w;  // sh0 == 1.0

    float el[10];
    {
        const float2* ep = (const float2*)(elenS + sidx * 10);
#pragma unroll
        for (int j = 0; j < 5; ++j) { float2 t = ep[j]; el[j * 2] = t.x; el[j * 2 + 1] = t.y; }
    }
    float h[16];
    {
        float acc[16];
#pragma unroll
        for (int j = 0; j < 16; ++j) acc[j] = 0.f;
#pragma unroll
        for (int c = 0; c < 10; ++c) {
            float ec = el[c];
#pragma unroll
            for (int j = 0; j < 16; ++j) acc[j] = fmaf(ec, Wv1[c * 16 + j], acc[j]);
        }
#pragma unroll
        for (int j = 0; j < 16; ++j) {
            float s = acc[j] * RS10;
            h[j] = alpha * (s / (1.f + __expf(-s)));   // alpha folded: v linear in h
        }
    }

    const float4* f4 = (const float4*)(feature + dst * 40);
    float xr[40];
#pragma unroll
    for (int i = 0; i < 10; ++i) {
        float4 t = f4[i];
        xr[i * 4 + 0] = t.x; xr[i * 4 + 1] = t.y; xr[i * 4 + 2] = t.z; xr[i * 4 + 3] = t.w;
    }
    float x0[16];
#pragma unroll
    for (int i = 0; i < 16; ++i) x0[i] = xr[i];
    float x1[8][3], d1[8], cx[8][3];
#pragma unroll
    for (int i = 0; i < 8; ++i) {
        float a = xr[16 + i * 3 + 0], b = xr[16 + i * 3 + 1], c = xr[16 + i * 3 + 2];
        x1[i][0] = a; x1[i][1] = b; x1[i][2] = c;
        d1[i] = a * sh1x + b * sh1y + c * sh1z;
        cx[i][0] = b * sh1z - c * sh1y;
        cx[i][1] = c * sh1x - a * sh1z;
        cx[i][2] = a * sh1y - b * sh1x;
    }

    float* orow = out + src * 40;

    // scalar (l=0) outputs of v: o in [0,16)
#pragma unroll 1
    for (int o = 0; o < 16; ++o) {
        float e000 = 0.f, e110 = 0.f;
#pragma unroll
        for (int i = 0; i < 16; ++i)
            e000 = fmaf(x0[i], wdot(W + (i * 16 + o) * 16, h), e000);
#pragma unroll
        for (int i = 0; i < 8; ++i)
            e110 = fmaf(d1[i], wdot(W + ((256 + i * 16 + o)) * 16, h), e110);
        float vo = e000 + e110;            // constants folded; sh0==1; alpha in h
        vo = segsum(vo, addmask);
        if (head) atomicAdd(orow + o, vo);
    }
    // vector (l=1) outputs of v: o in [0,8)
#pragma unroll 1
    for (int o = 0; o < 8; ++o) {
        float c0 = 0.f;
#pragma unroll
        for (int i = 0; i < 16; ++i)
            c0 = fmaf(x0[i], wdot(W + ((384 + i * 8 + o)) * 16, h), c0);
        float s1x = 0.f, s1y = 0.f, s1z = 0.f, s2x = 0.f, s2y = 0.f, s2z = 0.f;
#pragma unroll
        for (int i = 0; i < 8; ++i) {
            float wa = wdot(WG + (i * 8 + o) * 16, h);          // W101 (global)
            float wb = wdot(WG + ((64 + i * 8 + o)) * 16, h);   // W111 (global)
            s1x = fmaf(x1[i][0], wa, s1x); s1y = fmaf(x1[i][1], wa, s1y); s1z = fmaf(x1[i][2], wa, s1z);
            s2x = fmaf(cx[i][0], wb, s2x); s2y = fmaf(cx[i][1], wb, s2y); s2z = fmaf(cx[i][2], wb, s2z);
        }
        float vx = s1x + fmaf(c0, sh1x, s2x);
        float vy = s1y + fmaf(c0, sh1y, s2y);
        float vz = s1z + fmaf(c0, sh1z, s2z);
        vx = segsum(vx, addmask);
        vy = segsum(vy, addmask);
        vz = segsum(vz, addmask);
        if (head) {
            atomicAdd(orow + 16 + o * 3 + 0, vx);
            atomicAdd(orow + 16 + o * 3 + 1, vy);
            atomicAdd(orow + 16 + o * 3 + 2, vz);
        }
    }
}

// ---------- host ----------
extern "C" void kernel_launch(void* const* d_in, const int* in_sizes, int n_in,
                              void* d_out, int out_size, void* d_ws, size_t ws_size,
                              hipStream_t stream) {
    const float* feature = (const float*)d_in[0];
    const int*   esrc    = (const int*)d_in[1];
    const int*   edst    = (const int*)d_in[2];
    const float* esh     = (const float*)d_in[3];
    const float* elen    = (const float*)d_in[4];
    const float* Wq0     = (const float*)d_in[5];
    const float* Wq1     = (const float*)d_in[6];
    const float* Wk1     = (const float*)d_in[7];
    const float* Wk2     = (const float*)d_in[8];
    const float* Wv1     = (const float*)d_in[9];
    const float* Wv2     = (const float*)d_in[10];
    float* out = (float*)d_out;

    float* ws = (float*)d_ws;
    float* qbuf     = ws;                         // 320000
    float* logitbuf = ws + 320000;                // 256000
    float* logZ     = ws + 576000;                // 16000
    float* Wk2t     = ws + 592000;                // 5120
    float* Wv2t     = ws + 597120;                // 10240
    int*   cnt      = (int*)(ws + 607360);        // 16000
    int*   rowstart = (int*)(ws + 623360);        // 16001
    int*   cursor   = (int*)(ws + 639361);        // 16000
    int*   srcS     = (int*)(ws + 655361);        // 256000
    int*   dstS     = (int*)(ws + 911361);        // 256000
    float* shS      = ws + 1167364;               // 1024000 (16B aligned)
    float* elenS    = ws + 2191364;               // 2560000 (8B aligned)

    hipMemsetAsync(cnt, 0, NN * sizeof(int), stream);
    hipMemsetAsync(out, 0, (size_t)out_size * sizeof(float), stream);

    prep_kernel<<<60, 256, 0, stream>>>(Wk2, Wv2, Wk2t, Wv2t);
    q_kernel<<<(NN + 255) / 256, 256, 0, stream>>>(feature, Wq0, Wq1, qbuf);
    hist_kernel<<<NE / 256, 256, 0, stream>>>(esrc, cnt);
    scan_kernel<<<1, 1024, 0, stream>>>(cnt, rowstart, cursor);
    scatter_kernel<<<NE / 256, 256, 0, stream>>>(esrc, edst, esh, elen, cursor,
                                                 srcS, dstS, shS, elenS);
    k_kernel<<<NE / 512, 512, 0, stream>>>(srcS, dstS, shS, elenS, feature, qbuf,
                                           Wk1, Wk2t, logitbuf);
    mz_kernel<<<(NN + 255) / 256, 256, 0, stream>>>(rowstart, logitbuf, logZ);
    v_kernel<<<NE / 512, 512, 0, stream>>>(srcS, dstS, shS, elenS, feature,
                                           logitbuf, logZ, Wv1, Wv2t, out);
}